// Round 1
// 582.580 us; speedup vs baseline: 1.1172x; 1.1172x over previous
//
#include <hip/hip_runtime.h>

typedef __bf16 bf16x8 __attribute__((ext_vector_type(8)));
typedef float f32x4 __attribute__((ext_vector_type(4)));
typedef short s16x4 __attribute__((ext_vector_type(4)));

__device__ __forceinline__ unsigned short f2bf(float f) {
  unsigned int u = __float_as_uint(f);
  u += 0x7fffu + ((u >> 16) & 1u);           // round-to-nearest-even
  return (unsigned short)(u >> 16);
}
__device__ __forceinline__ float bf2f(unsigned short u) {
  return __uint_as_float(((unsigned)u) << 16);
}

// Convert the four 128x128 fp32 weight matrices to bf16 in workspace.
// Layout: Wq @ 0, Wk @ 16384, Wv @ 32768, Wo @ 49152 (elements).
__global__ __launch_bounds__(256) void wcvt(const float* __restrict__ Wq,
                                            const float* __restrict__ Wk,
                                            const float* __restrict__ Wv,
                                            const float* __restrict__ Wo,
                                            unsigned short* __restrict__ dst) {
  int i = blockIdx.x * 256 + threadIdx.x;    // 0..16383
  dst[i]          = f2bf(Wq[i]);
  dst[16384 + i]  = f2bf(Wk[i]);
  dst[32768 + i]  = f2bf(Wv[i]);
  dst[49152 + i]  = f2bf(Wo[i]);
}

// ---------------------------------------------------------------------------
// K1: one block per node, 256 threads = 4 waves, ONE WAVE PER HEAD.
// Exploits fragment identities:
//   - S' = K@Q^T C-frag (col=l16=q, row=quad*4+r=k)  ==  P A-frag of
//     mfma_16x16x16 (row=l16=q, k=quad*4+j), j=r  -> P never leaves registers.
//   - V-projection C-frag (col=l16=d, row=quad*4+r=k) == PV B-frag -> V stays
//     in registers; softmax 1/sum folds into the per-band V fragment.
// Only Q and K transpose through a wave-PRIVATE LDS buffer (no barriers).
// Single __syncthreads (after x staging). O written fp32 to d_out; the
// output projection runs as a separate in-place GEMM kernel (oproj).
// LDS: 96*136*2 + 4*96*36*2 = 26112 + 27648 = 53760 B -> 3 blocks/CU.
// ---------------------------------------------------------------------------
__global__ __launch_bounds__(256, 4) void attn_k1(
    const float* __restrict__ x, const float* __restrict__ bk,
    const float* __restrict__ bv, const unsigned short* __restrict__ Wbf,
    float* __restrict__ out) {
  __shared__ unsigned short Xs[96 * 136];    // x as bf16, padded stride
  __shared__ unsigned short priv[4][96 * 36]; // per-wave Q-then-K transpose buf

  const int tid  = threadIdx.x;
  const int wid  = tid >> 6;       // 0..3 == head
  const int lane = tid & 63;
  const int quad = lane >> 4;      // 0..3
  const int l16  = lane & 15;
  const int node = blockIdx.x;
  const int h    = wid;

  // ---- stage x (fp32 global) -> bf16 LDS, coalesced float4 ----
  const float4* xb = (const float4*)(x + (size_t)node * (96 * 128));
  #pragma unroll
  for (int it = 0; it < 12; ++it) {
    int i4 = tid + it * 256;                 // 0..3071
    float4 v = xb[i4];
    int f = i4 << 2;
    int row = f >> 7, col = f & 127;
    ushort4 w;
    w.x = f2bf(v.x); w.y = f2bf(v.y); w.z = f2bf(v.z); w.w = f2bf(v.w);
    *(ushort4*)&Xs[row * 136 + col] = w;
  }
  __syncthreads();                           // the ONLY block barrier

  unsigned short* Bp = &priv[wid][0];
  const unsigned short* WqB = Wbf;
  const unsigned short* WkB = Wbf + 16384;
  const unsigned short* WvB = Wbf + 32768;

  bf16x8 wfr[2][4];

  // ---- V projection: C-frags ARE the PV B-frags (K=16). Keep in regs. ----
  s16x4 vb[6][2];
  {
    #pragma unroll
    for (int nt = 0; nt < 2; ++nt)
      #pragma unroll
      for (int ks = 0; ks < 4; ++ks)
        wfr[nt][ks] = *(const bf16x8*)(WvB + (size_t)(h * 32 + nt * 16 + l16) * 128 + ks * 32 + quad * 8);
    f32x4 vacc[6][2];
    #pragma unroll
    for (int mt = 0; mt < 6; ++mt) { vacc[mt][0] = (f32x4){0,0,0,0}; vacc[mt][1] = (f32x4){0,0,0,0}; }
    #pragma unroll
    for (int mt = 0; mt < 6; ++mt)
      #pragma unroll
      for (int ks = 0; ks < 4; ++ks) {
        bf16x8 afr = *(const bf16x8*)&Xs[(mt * 16 + l16) * 136 + ks * 32 + quad * 8];
        vacc[mt][0] = __builtin_amdgcn_mfma_f32_16x16x32_bf16(afr, wfr[0][ks], vacc[mt][0], 0, 0, 0);
        vacc[mt][1] = __builtin_amdgcn_mfma_f32_16x16x32_bf16(afr, wfr[1][ks], vacc[mt][1], 0, 0, 0);
      }
    float bv0 = bv[h * 32 + l16], bv1 = bv[h * 32 + 16 + l16];
    #pragma unroll
    for (int kt = 0; kt < 6; ++kt)
      #pragma unroll
      for (int r = 0; r < 4; ++r) {
        vb[kt][0][r] = (short)f2bf(vacc[kt][0][r] + bv0);
        vb[kt][1][r] = (short)f2bf(vacc[kt][1][r] + bv1);
      }
  }

  // ---- Q projection -> private LDS (transpose) -> B-frags in regs ----
  // bq cancels in softmax-over-q, skip it.
  {
    #pragma unroll
    for (int nt = 0; nt < 2; ++nt)
      #pragma unroll
      for (int ks = 0; ks < 4; ++ks)
        wfr[nt][ks] = *(const bf16x8*)(WqB + (size_t)(h * 32 + nt * 16 + l16) * 128 + ks * 32 + quad * 8);
    #pragma unroll
    for (int mt = 0; mt < 6; ++mt) {
      f32x4 a0 = {0,0,0,0}, a1 = {0,0,0,0};
      #pragma unroll
      for (int ks = 0; ks < 4; ++ks) {
        bf16x8 afr = *(const bf16x8*)&Xs[(mt * 16 + l16) * 136 + ks * 32 + quad * 8];
        a0 = __builtin_amdgcn_mfma_f32_16x16x32_bf16(afr, wfr[0][ks], a0, 0, 0, 0);
        a1 = __builtin_amdgcn_mfma_f32_16x16x32_bf16(afr, wfr[1][ks], a1, 0, 0, 0);
      }
      #pragma unroll
      for (int r = 0; r < 4; ++r) {
        Bp[(mt * 16 + quad * 4 + r) * 36 + l16]      = f2bf(a0[r]);
        Bp[(mt * 16 + quad * 4 + r) * 36 + 16 + l16] = f2bf(a1[r]);
      }
    }
  }
  union U16 { uint2 u[2]; bf16x8 v; };
  bf16x8 qb[6];
  #pragma unroll
  for (int qt = 0; qt < 6; ++qt) {
    // stride 36 shorts = 72 B: rows are 8B-aligned, read as two b64s
    const unsigned short* p = &Bp[(qt * 16 + l16) * 36 + quad * 8];
    U16 t; t.u[0] = *(const uint2*)p; t.u[1] = *(const uint2*)(p + 4);
    qb[qt] = t.v;
  }

  // ---- K projection -> SAME private buffer (Q already in regs) ----
  {
    #pragma unroll
    for (int nt = 0; nt < 2; ++nt)
      #pragma unroll
      for (int ks = 0; ks < 4; ++ks)
        wfr[nt][ks] = *(const bf16x8*)(WkB + (size_t)(h * 32 + nt * 16 + l16) * 128 + ks * 32 + quad * 8);
    float bk0 = bk[h * 32 + l16], bk1 = bk[h * 32 + 16 + l16];
    #pragma unroll
    for (int kt = 0; kt < 6; ++kt) {
      f32x4 a0 = {0,0,0,0}, a1 = {0,0,0,0};
      #pragma unroll
      for (int ks = 0; ks < 4; ++ks) {
        bf16x8 afr = *(const bf16x8*)&Xs[(kt * 16 + l16) * 136 + ks * 32 + quad * 8];
        a0 = __builtin_amdgcn_mfma_f32_16x16x32_bf16(afr, wfr[0][ks], a0, 0, 0, 0);
        a1 = __builtin_amdgcn_mfma_f32_16x16x32_bf16(afr, wfr[1][ks], a1, 0, 0, 0);
      }
      #pragma unroll
      for (int r = 0; r < 4; ++r) {
        Bp[(kt * 16 + quad * 4 + r) * 36 + l16]      = f2bf(a0[r] + bk0);
        Bp[(kt * 16 + quad * 4 + r) * 36 + 16 + l16] = f2bf(a1[r] + bk1);
      }
    }
  }

  // ---- attention: per 16-row k-band; P and V never touch LDS ----
  // softmax over q, no max-subtraction (|S*scale| ~ 0.5, exp2 is safe; exact
  // by shift-invariance).
  const float SC = 0.17677669529663687f * 1.4426950408889634f; // (1/sqrt(32))*log2(e)
  f32x4 o[6][2];
  #pragma unroll
  for (int qt = 0; qt < 6; ++qt) { o[qt][0] = (f32x4){0,0,0,0}; o[qt][1] = (f32x4){0,0,0,0}; }

  #pragma unroll
  for (int band = 0; band < 6; ++band) {
    const unsigned short* kp = &Bp[(band * 16 + l16) * 36 + quad * 8];
    U16 tk; tk.u[0] = *(const uint2*)kp; tk.u[1] = *(const uint2*)(kp + 4);
    bf16x8 ka = tk.v;

    float sum0 = 0.f, sum1 = 0.f, sum2 = 0.f, sum3 = 0.f;
    s16x4 P[6];
    #pragma unroll
    for (int qt = 0; qt < 6; ++qt) {
      f32x4 z = {0,0,0,0};
      f32x4 s = __builtin_amdgcn_mfma_f32_16x16x32_bf16(ka, qb[qt], z, 0, 0, 0);
      float e0 = exp2f(s[0] * SC), e1 = exp2f(s[1] * SC);
      float e2 = exp2f(s[2] * SC), e3 = exp2f(s[3] * SC);
      sum0 += e0; sum1 += e1; sum2 += e2; sum3 += e3;
      P[qt][0] = (short)f2bf(e0); P[qt][1] = (short)f2bf(e1);
      P[qt][2] = (short)f2bf(e2); P[qt][3] = (short)f2bf(e3);
    }
    #pragma unroll
    for (int d = 1; d < 16; d <<= 1) {
      sum0 += __shfl_xor(sum0, d, 64);
      sum1 += __shfl_xor(sum1, d, 64);
      sum2 += __shfl_xor(sum2, d, 64);
      sum3 += __shfl_xor(sum3, d, 64);
    }
    float rinv[4] = {1.f / sum0, 1.f / sum1, 1.f / sum2, 1.f / sum3};
    // fold 1/sum (per k-row = quad*4+j) into this band's V fragment
    #pragma unroll
    for (int nt = 0; nt < 2; ++nt)
      #pragma unroll
      for (int j = 0; j < 4; ++j)
        vb[band][nt][j] = (short)f2bf(bf2f((unsigned short)vb[band][nt][j]) * rinv[j]);
    #pragma unroll
    for (int qt = 0; qt < 6; ++qt) {
      o[qt][0] = __builtin_amdgcn_mfma_f32_16x16x16bf16_1k(P[qt], vb[band][0], o[qt][0], 0, 0, 0);
      o[qt][1] = __builtin_amdgcn_mfma_f32_16x16x16bf16_1k(P[qt], vb[band][1], o[qt][1], 0, 0, 0);
    }
  }

  // ---- store O (pre-projection) as fp32 into d_out; oproj projects in-place
  float* ob = out + (size_t)node * (96 * 128) + h * 32;
  #pragma unroll
  for (int qt = 0; qt < 6; ++qt)
    #pragma unroll
    for (int nt = 0; nt < 2; ++nt)
      #pragma unroll
      for (int r = 0; r < 4; ++r)
        ob[(qt * 16 + quad * 4 + r) * 128 + nt * 16 + l16] = o[qt][nt][r];
}

// ---------------------------------------------------------------------------
// K2: out = O @ Wo^T + bo, IN PLACE on d_out. 128-row tile per block,
// 4 waves x 32 rows. Each wave loads all its A-frags (its own rows only)
// into registers before any store; stores of rows 0-15 are disjoint from
// loads of rows 16-31, so in-place is race-free. Memory-bound (~400 MB).
// ---------------------------------------------------------------------------
__global__ __launch_bounds__(256) void oproj(float* __restrict__ io,
                                             const unsigned short* __restrict__ Wbf,
                                             const float* __restrict__ bo) {
  const int tid  = threadIdx.x;
  const int wid  = tid >> 6;
  const int lane = tid & 63;
  const int quad = lane >> 4;
  const int l16  = lane & 15;
  const size_t row0 = (size_t)blockIdx.x * 128 + wid * 32;

  // load + convert A-frags (this wave's 32 rows) fully into registers
  bf16x8 afr[2][4];
  #pragma unroll
  for (int mt = 0; mt < 2; ++mt)
    #pragma unroll
    for (int ks = 0; ks < 4; ++ks) {
      const float* p = io + (row0 + mt * 16 + l16) * 128 + ks * 32 + quad * 8;
      float4 lo = *(const float4*)p;
      float4 hi = *(const float4*)(p + 4);
      bf16x8 t;
      t[0] = (__bf16)0; // overwritten below; keeps initializer simple
      unsigned short u0 = f2bf(lo.x), u1 = f2bf(lo.y), u2 = f2bf(lo.z), u3 = f2bf(lo.w);
      unsigned short u4 = f2bf(hi.x), u5 = f2bf(hi.y), u6 = f2bf(hi.z), u7 = f2bf(hi.w);
      union { unsigned short s[8]; bf16x8 v; } cv;
      cv.s[0] = u0; cv.s[1] = u1; cv.s[2] = u2; cv.s[3] = u3;
      cv.s[4] = u4; cv.s[5] = u5; cv.s[6] = u6; cv.s[7] = u7;
      afr[mt][ks] = cv.v;
    }

  const unsigned short* Wo = Wbf + 49152;
  #pragma unroll
  for (int nt = 0; nt < 8; ++nt) {
    f32x4 acc0 = {0,0,0,0}, acc1 = {0,0,0,0};
    #pragma unroll
    for (int ks = 0; ks < 4; ++ks) {
      bf16x8 w = *(const bf16x8*)(Wo + (size_t)(nt * 16 + l16) * 128 + ks * 32 + quad * 8);
      acc0 = __builtin_amdgcn_mfma_f32_16x16x32_bf16(afr[0][ks], w, acc0, 0, 0, 0);
      acc1 = __builtin_amdgcn_mfma_f32_16x16x32_bf16(afr[1][ks], w, acc1, 0, 0, 0);
    }
    float bias = bo[nt * 16 + l16];
    #pragma unroll
    for (int r = 0; r < 4; ++r) {
      io[(row0 + quad * 4 + r) * 128 + nt * 16 + l16]      = acc0[r] + bias;
      io[(row0 + 16 + quad * 4 + r) * 128 + nt * 16 + l16] = acc1[r] + bias;
    }
  }
}

extern "C" void kernel_launch(void* const* d_in, const int* in_sizes, int n_in,
                              void* d_out, int out_size, void* d_ws, size_t ws_size,
                              hipStream_t stream) {
  const float* x  = (const float*)d_in[0];
  const float* Wq = (const float*)d_in[1];
  // d_in[2] = bq: cancels in softmax over q
  const float* Wk = (const float*)d_in[3];
  const float* bk = (const float*)d_in[4];
  const float* Wv = (const float*)d_in[5];
  const float* bv = (const float*)d_in[6];
  const float* Wo = (const float*)d_in[7];
  const float* bo = (const float*)d_in[8];
  int B_N = in_sizes[0] / (96 * 128);        // 4096

  unsigned short* Wbf = (unsigned short*)d_ws;  // 4 * 16384 bf16 = 128 KiB
  wcvt<<<64, 256, 0, stream>>>(Wq, Wk, Wv, Wo, Wbf);
  attn_k1<<<B_N, 256, 0, stream>>>(x, bk, bv, Wbf, (float*)d_out);
  oproj<<<(B_N * 96) / 128, 256, 0, stream>>>((float*)d_out, Wbf, bo);
}

// Round 2
// 406.677 us; speedup vs baseline: 1.6005x; 1.4325x over previous
//
#include <hip/hip_runtime.h>

typedef __bf16 bf16x8 __attribute__((ext_vector_type(8)));
typedef float f32x4 __attribute__((ext_vector_type(4)));
typedef short s16x4 __attribute__((ext_vector_type(4)));

__device__ __forceinline__ unsigned short f2bf(float f) {
  unsigned int u = __float_as_uint(f);
  u += 0x7fffu + ((u >> 16) & 1u);           // round-to-nearest-even
  return (unsigned short)(u >> 16);
}
__device__ __forceinline__ float bf2f(unsigned short u) {
  return __uint_as_float(((unsigned)u) << 16);
}

// Convert the four 128x128 fp32 weight matrices to bf16 in workspace.
// Layout: Wq @ 0, Wk @ 16384, Wv @ 32768, Wo @ 49152 (elements).
__global__ __launch_bounds__(256) void wcvt(const float* __restrict__ Wq,
                                            const float* __restrict__ Wk,
                                            const float* __restrict__ Wv,
                                            const float* __restrict__ Wo,
                                            unsigned short* __restrict__ dst) {
  int i = blockIdx.x * 256 + threadIdx.x;    // 0..16383
  dst[i]          = f2bf(Wq[i]);
  dst[16384 + i]  = f2bf(Wk[i]);
  dst[32768 + i]  = f2bf(Wv[i]);
  dst[49152 + i]  = f2bf(Wo[i]);
}

// ---------------------------------------------------------------------------
// Fully fused: one block per node, 256 threads = 4 waves, ONE WAVE PER HEAD.
// Fragment identities keep P and V in registers (see round-1 notes).
// NEW: out-projection fused. After attention, each wave parks its head's O
// (96x32 bf16) in its OWN priv buffer (K is dead; priv stays wave-private so
// no extra race), ONE barrier, then wave w computes output columns
// [32w,32w+32): A-frags from priv[ks] (k-slice ks of the 128-dim == head ks),
// B-frags from Wo_bf, 48 MFMAs, fp32 stores + bias direct to d_out.
// Barriers per block: 2. LDS: 96*136*2 + 4*96*36*2 = 53760 B -> 3 blocks/CU.
// ---------------------------------------------------------------------------
__global__ __launch_bounds__(256, 3) void attn_k1(
    const float* __restrict__ x, const float* __restrict__ bk,
    const float* __restrict__ bv, const float* __restrict__ bo,
    const unsigned short* __restrict__ Wbf, float* __restrict__ out) {
  __shared__ unsigned short Xs[96 * 136];     // x as bf16, padded stride
  __shared__ unsigned short priv[4][96 * 36]; // per-wave Q->K->O buffer

  const int tid  = threadIdx.x;
  const int wid  = tid >> 6;       // 0..3 == head
  const int lane = tid & 63;
  const int quad = lane >> 4;      // 0..3
  const int l16  = lane & 15;
  const int node = blockIdx.x;
  const int h    = wid;

  // ---- stage x (fp32 global) -> bf16 LDS, coalesced float4 ----
  const float4* xb = (const float4*)(x + (size_t)node * (96 * 128));
  #pragma unroll
  for (int it = 0; it < 12; ++it) {
    int i4 = tid + it * 256;                 // 0..3071
    float4 v = xb[i4];
    int f = i4 << 2;
    int row = f >> 7, col = f & 127;
    ushort4 w;
    w.x = f2bf(v.x); w.y = f2bf(v.y); w.z = f2bf(v.z); w.w = f2bf(v.w);
    *(ushort4*)&Xs[row * 136 + col] = w;
  }
  __syncthreads();                           // barrier #1

  unsigned short* Bp = &priv[wid][0];
  const unsigned short* WqB = Wbf;
  const unsigned short* WkB = Wbf + 16384;
  const unsigned short* WvB = Wbf + 32768;

  bf16x8 wfr[2][4];

  // ---- V projection: C-frags ARE the PV B-frags (K=16). Keep in regs. ----
  s16x4 vb[6][2];
  {
    #pragma unroll
    for (int nt = 0; nt < 2; ++nt)
      #pragma unroll
      for (int ks = 0; ks < 4; ++ks)
        wfr[nt][ks] = *(const bf16x8*)(WvB + (size_t)(h * 32 + nt * 16 + l16) * 128 + ks * 32 + quad * 8);
    f32x4 vacc[6][2];
    #pragma unroll
    for (int mt = 0; mt < 6; ++mt) { vacc[mt][0] = (f32x4){0,0,0,0}; vacc[mt][1] = (f32x4){0,0,0,0}; }
    #pragma unroll
    for (int mt = 0; mt < 6; ++mt)
      #pragma unroll
      for (int ks = 0; ks < 4; ++ks) {
        bf16x8 afr = *(const bf16x8*)&Xs[(mt * 16 + l16) * 136 + ks * 32 + quad * 8];
        vacc[mt][0] = __builtin_amdgcn_mfma_f32_16x16x32_bf16(afr, wfr[0][ks], vacc[mt][0], 0, 0, 0);
        vacc[mt][1] = __builtin_amdgcn_mfma_f32_16x16x32_bf16(afr, wfr[1][ks], vacc[mt][1], 0, 0, 0);
      }
    float bv0 = bv[h * 32 + l16], bv1 = bv[h * 32 + 16 + l16];
    #pragma unroll
    for (int kt = 0; kt < 6; ++kt)
      #pragma unroll
      for (int r = 0; r < 4; ++r) {
        vb[kt][0][r] = (short)f2bf(vacc[kt][0][r] + bv0);
        vb[kt][1][r] = (short)f2bf(vacc[kt][1][r] + bv1);
      }
  }

  // ---- Q projection -> private LDS (transpose) -> B-frags in regs ----
  // bq cancels in softmax-over-q, skip it.
  {
    #pragma unroll
    for (int nt = 0; nt < 2; ++nt)
      #pragma unroll
      for (int ks = 0; ks < 4; ++ks)
        wfr[nt][ks] = *(const bf16x8*)(WqB + (size_t)(h * 32 + nt * 16 + l16) * 128 + ks * 32 + quad * 8);
    #pragma unroll
    for (int mt = 0; mt < 6; ++mt) {
      f32x4 a0 = {0,0,0,0}, a1 = {0,0,0,0};
      #pragma unroll
      for (int ks = 0; ks < 4; ++ks) {
        bf16x8 afr = *(const bf16x8*)&Xs[(mt * 16 + l16) * 136 + ks * 32 + quad * 8];
        a0 = __builtin_amdgcn_mfma_f32_16x16x32_bf16(afr, wfr[0][ks], a0, 0, 0, 0);
        a1 = __builtin_amdgcn_mfma_f32_16x16x32_bf16(afr, wfr[1][ks], a1, 0, 0, 0);
      }
      #pragma unroll
      for (int r = 0; r < 4; ++r) {
        Bp[(mt * 16 + quad * 4 + r) * 36 + l16]      = f2bf(a0[r]);
        Bp[(mt * 16 + quad * 4 + r) * 36 + 16 + l16] = f2bf(a1[r]);
      }
    }
  }
  union U16 { uint2 u[2]; bf16x8 v; };
  bf16x8 qb[6];
  #pragma unroll
  for (int qt = 0; qt < 6; ++qt) {
    // stride 36 shorts = 72 B: rows are 8B-aligned, read as two b64s
    const unsigned short* p = &Bp[(qt * 16 + l16) * 36 + quad * 8];
    U16 t; t.u[0] = *(const uint2*)p; t.u[1] = *(const uint2*)(p + 4);
    qb[qt] = t.v;
  }

  // ---- K projection -> SAME private buffer (Q already in regs) ----
  {
    #pragma unroll
    for (int nt = 0; nt < 2; ++nt)
      #pragma unroll
      for (int ks = 0; ks < 4; ++ks)
        wfr[nt][ks] = *(const bf16x8*)(WkB + (size_t)(h * 32 + nt * 16 + l16) * 128 + ks * 32 + quad * 8);
    float bk0 = bk[h * 32 + l16], bk1 = bk[h * 32 + 16 + l16];
    #pragma unroll
    for (int kt = 0; kt < 6; ++kt) {
      f32x4 a0 = {0,0,0,0}, a1 = {0,0,0,0};
      #pragma unroll
      for (int ks = 0; ks < 4; ++ks) {
        bf16x8 afr = *(const bf16x8*)&Xs[(kt * 16 + l16) * 136 + ks * 32 + quad * 8];
        a0 = __builtin_amdgcn_mfma_f32_16x16x32_bf16(afr, wfr[0][ks], a0, 0, 0, 0);
        a1 = __builtin_amdgcn_mfma_f32_16x16x32_bf16(afr, wfr[1][ks], a1, 0, 0, 0);
      }
      #pragma unroll
      for (int r = 0; r < 4; ++r) {
        Bp[(kt * 16 + quad * 4 + r) * 36 + l16]      = f2bf(a0[r] + bk0);
        Bp[(kt * 16 + quad * 4 + r) * 36 + 16 + l16] = f2bf(a1[r] + bk1);
      }
    }
  }

  // ---- attention: per 16-row k-band; P and V never touch LDS ----
  // softmax over q, no max-subtraction (|S*scale| ~ 0.5, exp2 is safe; exact
  // by shift-invariance).
  const float SC = 0.17677669529663687f * 1.4426950408889634f; // (1/sqrt(32))*log2(e)
  f32x4 o[6][2];
  #pragma unroll
  for (int qt = 0; qt < 6; ++qt) { o[qt][0] = (f32x4){0,0,0,0}; o[qt][1] = (f32x4){0,0,0,0}; }

  #pragma unroll
  for (int band = 0; band < 6; ++band) {
    const unsigned short* kp = &Bp[(band * 16 + l16) * 36 + quad * 8];
    U16 tk; tk.u[0] = *(const uint2*)kp; tk.u[1] = *(const uint2*)(kp + 4);
    bf16x8 ka = tk.v;

    float sum0 = 0.f, sum1 = 0.f, sum2 = 0.f, sum3 = 0.f;
    s16x4 P[6];
    #pragma unroll
    for (int qt = 0; qt < 6; ++qt) {
      f32x4 z = {0,0,0,0};
      f32x4 s = __builtin_amdgcn_mfma_f32_16x16x32_bf16(ka, qb[qt], z, 0, 0, 0);
      float e0 = exp2f(s[0] * SC), e1 = exp2f(s[1] * SC);
      float e2 = exp2f(s[2] * SC), e3 = exp2f(s[3] * SC);
      sum0 += e0; sum1 += e1; sum2 += e2; sum3 += e3;
      P[qt][0] = (short)f2bf(e0); P[qt][1] = (short)f2bf(e1);
      P[qt][2] = (short)f2bf(e2); P[qt][3] = (short)f2bf(e3);
    }
    #pragma unroll
    for (int d = 1; d < 16; d <<= 1) {
      sum0 += __shfl_xor(sum0, d, 64);
      sum1 += __shfl_xor(sum1, d, 64);
      sum2 += __shfl_xor(sum2, d, 64);
      sum3 += __shfl_xor(sum3, d, 64);
    }
    float rinv[4] = {1.f / sum0, 1.f / sum1, 1.f / sum2, 1.f / sum3};
    // fold 1/sum (per k-row = quad*4+j) into this band's V fragment
    #pragma unroll
    for (int nt = 0; nt < 2; ++nt)
      #pragma unroll
      for (int j = 0; j < 4; ++j)
        vb[band][nt][j] = (short)f2bf(bf2f((unsigned short)vb[band][nt][j]) * rinv[j]);
    #pragma unroll
    for (int qt = 0; qt < 6; ++qt) {
      o[qt][0] = __builtin_amdgcn_mfma_f32_16x16x16bf16_1k(P[qt], vb[band][0], o[qt][0], 0, 0, 0);
      o[qt][1] = __builtin_amdgcn_mfma_f32_16x16x16bf16_1k(P[qt], vb[band][1], o[qt][1], 0, 0, 0);
    }
  }

  // ---- park O (96x32 bf16) in OWN priv buffer (K dead; still wave-private)
  #pragma unroll
  for (int qt = 0; qt < 6; ++qt)
    #pragma unroll
    for (int nt = 0; nt < 2; ++nt)
      #pragma unroll
      for (int r = 0; r < 4; ++r)
        Bp[(qt * 16 + quad * 4 + r) * 36 + nt * 16 + l16] = f2bf(o[qt][nt][r]);
  __syncthreads();                           // barrier #2: O exchange

  // ---- fused out-projection: wave w -> output columns [32w, 32w+32) ----
  // A-frag k-slice ks of the 128-dim inner product == head ks's O block.
  {
    const unsigned short* WoB = Wbf + 49152;
    bf16x8 wo[2][4];
    #pragma unroll
    for (int nt = 0; nt < 2; ++nt)
      #pragma unroll
      for (int ks = 0; ks < 4; ++ks)
        wo[nt][ks] = *(const bf16x8*)(WoB + (size_t)(wid * 32 + nt * 16 + l16) * 128 + ks * 32 + quad * 8);
    float bo0 = bo[wid * 32 + l16], bo1 = bo[wid * 32 + 16 + l16];
    float* ob = out + (size_t)node * (96 * 128) + wid * 32;
    #pragma unroll
    for (int mt = 0; mt < 6; ++mt) {
      f32x4 a0 = {0,0,0,0}, a1 = {0,0,0,0};
      #pragma unroll
      for (int ks = 0; ks < 4; ++ks) {
        const unsigned short* p = &priv[ks][(mt * 16 + l16) * 36 + quad * 8];
        U16 t; t.u[0] = *(const uint2*)p; t.u[1] = *(const uint2*)(p + 4);
        a0 = __builtin_amdgcn_mfma_f32_16x16x32_bf16(t.v, wo[0][ks], a0, 0, 0, 0);
        a1 = __builtin_amdgcn_mfma_f32_16x16x32_bf16(t.v, wo[1][ks], a1, 0, 0, 0);
      }
      #pragma unroll
      for (int r = 0; r < 4; ++r) {
        int row = mt * 16 + quad * 4 + r;
        ob[row * 128 + l16]      = a0[r] + bo0;
        ob[row * 128 + 16 + l16] = a1[r] + bo1;
      }
    }
  }
}

extern "C" void kernel_launch(void* const* d_in, const int* in_sizes, int n_in,
                              void* d_out, int out_size, void* d_ws, size_t ws_size,
                              hipStream_t stream) {
  const float* x  = (const float*)d_in[0];
  const float* Wq = (const float*)d_in[1];
  // d_in[2] = bq: cancels in softmax over q
  const float* Wk = (const float*)d_in[3];
  const float* bk = (const float*)d_in[4];
  const float* Wv = (const float*)d_in[5];
  const float* bv = (const float*)d_in[6];
  const float* Wo = (const float*)d_in[7];
  const float* bo = (const float*)d_in[8];
  int B_N = in_sizes[0] / (96 * 128);        // 4096

  unsigned short* Wbf = (unsigned short*)d_ws;  // 4 * 16384 bf16 = 128 KiB
  wcvt<<<64, 256, 0, stream>>>(Wq, Wk, Wv, Wo, Wbf);
  attn_k1<<<B_N, 256, 0, stream>>>(x, bk, bv, bo, Wbf, (float*)d_out);
}